// Round 2
// baseline (1050.917 us; speedup 1.0000x reference)
//
#include <hip/hip_runtime.h>
#include <hip/hip_bf16.h>

#define BS 4
#define NN 256
#define DX 256
#define DE 64
#define DY 64
#define NH 8
#define DF 32
#define INV_SQRT_DF 0.17677669529663687f

typedef unsigned short ushort_t;
typedef unsigned int uint32;

__device__ __forceinline__ float b2f(ushort_t u) {
  union { uint32 i; float f; } v; v.i = ((uint32)u) << 16; return v.f;
}
__device__ __forceinline__ ushort_t f2b(float f) {
  union { float f; uint32 i; } v; v.f = f;
  uint32 x = v.i;
  x += ((x >> 16) & 1u) + 0x7FFFu;   // round-to-nearest-even
  return (ushort_t)(x >> 16);
}

// ---------------- Q/K/V projections: (X @ W + b) * x_mask ----------------
__global__ __launch_bounds__(256) void k_qkv(const float* X, const float* nmask,
    const float* Wq, const float* bq, const float* Wk, const float* bk,
    const float* Wv, const float* bv, float* Q, float* K, float* V) {
  int blk = blockIdx.x;            // b*N + i
  int t = threadIdx.x;
  __shared__ float sX[DX];
  sX[t] = X[(size_t)blk * DX + t];
  __syncthreads();
  float m = nmask[blk];
  float aq = bq[t], ak = bk[t], av = bv[t];
  #pragma unroll 4
  for (int k = 0; k < DX; ++k) {
    float x = sX[k];
    aq += x * Wq[k * DX + t];
    ak += x * Wk[k * DX + t];
    av += x * Wv[k * DX + t];
  }
  size_t o = (size_t)blk * DX + t;
  Q[o] = aq * m; K[o] = ak * m; V[o] = av * m;
}

// ---------------- X stats: mean/min/max/std(ddof=1) over axis 1 ----------------
__global__ __launch_bounds__(256) void k_xstats(const float* X, float* xs) {
  int b = blockIdx.x; int d = threadIdx.x;
  float s = 0.f, ss = 0.f, mn = 1e30f, mx = -1e30f;
  for (int i = 0; i < NN; ++i) {
    float v = X[((size_t)b * NN + i) * DX + d];
    s += v; ss += v * v; mn = fminf(mn, v); mx = fmaxf(mx, v);
  }
  float mean = s / (float)NN;
  float var = (ss - (float)NN * mean * mean) / (float)(NN - 1);
  var = fmaxf(var, 0.f);
  float* o = xs + b * 4 * DX;
  o[d] = mean; o[DX + d] = mn; o[2 * DX + d] = mx; o[3 * DX + d] = sqrtf(var);
}

// ---------------- ye2+1, yx2+1 ----------------
__global__ __launch_bounds__(256) void k_ymul(const float* y,
    const float* Wye, const float* bye,
    const float* Wyx, const float* byx, float* yep1, float* yxp1) {
  int b = blockIdx.x; int t = threadIdx.x;
  __shared__ float sy[DY];
  if (t < DY) sy[t] = y[b * DY + t];
  __syncthreads();
  float ae = bye[t], ax = byx[t];
  #pragma unroll
  for (int k = 0; k < DY; ++k) {
    float v = sy[k];
    ae += v * Wye[k * DX + t];
    ax += v * Wyx[k * DX + t];
  }
  yep1[b * DX + t] = ae + 1.0f;
  yxp1[b * DX + t] = ax + 1.0f;
}

// ---------------- fused main: E1, Y, online softmax, weighted_V, newE, E-stat partials ----
__global__ __launch_bounds__(256) void k_main(
    const float* E, const float* nmask,
    const float* Wemul, const float* bemul,
    const float* Weout, const float* beout,
    const float* Q, const float* K, const float* V,
    const float* yep1, const float* yxp1,
    float* newE, float* wvs, float* est) {
  int blk = blockIdx.x; int b = blk >> 8; int i = blk & 255;
  (void)i;
  int t = threadIdx.x;                    // t == channel c for phase 1
  __shared__ uint32 sWmul[32 * 256];      // packed bf16 pairs (k, k+1) for channel c
  __shared__ uint32 sWout[128 * 64];      // packed bf16 pairs (c, c+1) for out d
  __shared__ __align__(16) float sE[DE];
  __shared__ float sPre[DX];
  __shared__ float sPart[4 * 64];

  for (int idx = t; idx < 32 * 256; idx += 256) {
    int kp = idx >> 8, c = idx & 255;
    uint32 lo = f2b(Wemul[(2 * kp) * DX + c]);
    uint32 hi = f2b(Wemul[(2 * kp + 1) * DX + c]);
    sWmul[idx] = lo | (hi << 16);
  }
  for (int idx = t; idx < 128 * 64; idx += 256) {
    int cp = idx >> 6, d = idx & 63;
    uint32 lo = f2b(Weout[(2 * cp) * DE + d]);
    uint32 hi = f2b(Weout[(2 * cp + 1) * DE + d]);
    sWout[idx] = lo | (hi << 16);
  }
  float mi  = nmask[b * NN + (blk & 255)];
  float qc  = Q[(size_t)blk * DX + t];
  float ye  = yep1[b * DX + t];
  float yx  = yxp1[b * DX + t];
  float bem = bemul[t];
  int d2 = t & 63, qq = t >> 6;
  float beo = beout[d2];
  float m = -1e30f, l = 0.f, accv = 0.f;
  float es_s = 0.f, es_ss = 0.f, es_mn = 1e30f, es_mx = -1e30f;
  __syncthreads();

  const float2* sE2 = (const float2*)sE;
  const float* Erow_base = E + (size_t)blk * NN * DE;

  for (int j = 0; j < NN; ++j) {
    if (t < DE) sE[t] = Erow_base[j * DE + t];
    __syncthreads();
    float mj = nmask[b * NN + j];
    // E1 = (E_row @ W_e_mul + b) * mi * mj
    float a0 = 0.f, a1 = 0.f;
    #pragma unroll
    for (int kp = 0; kp < 32; kp += 2) {
      uint32 w0 = sWmul[(kp << 8) | t]; float2 e0 = sE2[kp];
      a0 += b2f((ushort_t)(w0 & 0xffffu)) * e0.x;
      a1 += b2f((ushort_t)(w0 >> 16)) * e0.y;
      uint32 w1 = sWmul[((kp + 1) << 8) | t]; float2 e1 = sE2[kp + 1];
      a0 += b2f((ushort_t)(w1 & 0xffffu)) * e1.x;
      a1 += b2f((ushort_t)(w1 >> 16)) * e1.y;
    }
    float E1 = (bem + a0 + a1) * mi * mj;
    float yv = qc * K[((size_t)(b * NN + j)) * DX + t] * INV_SQRT_DF * (E1 + 1.0f);
    // online softmax over j (masked), per channel
    if (mj > 0.f) {
      float nm = fmaxf(m, yv);
      float corr = __expf(m - nm);
      float p = __expf(yv - nm);
      float vv = V[((size_t)(b * NN + j)) * DX + t];
      l = l * corr + p;
      accv = accv * corr + p * vv;
      m = nm;
    }
    // E stats partials (raw E)
    if (t < DE) {
      float ev = sE[t];
      es_s += ev; es_ss += ev * ev;
      es_mn = fminf(es_mn, ev); es_mx = fmaxf(es_mx, ev);
    }
    // pre = (ye2+1) * Y  (f32 in LDS)
    sPre[t] = ye * yv;
    __syncthreads();
    // newE row = (pre @ W_e_out + b) * mi * mj  (4-way split over c)
    float p0 = 0.f, p1 = 0.f;
    const float2* sPre2 = (const float2*)sPre;
    #pragma unroll
    for (int u = 0; u < 32; u += 2) {
      int cp = qq * 32 + u;
      uint32 w = sWout[(cp << 6) | d2]; float2 pp = sPre2[cp];
      p0 += pp.x * b2f((ushort_t)(w & 0xffffu));
      p1 += pp.y * b2f((ushort_t)(w >> 16));
      uint32 w2 = sWout[((cp + 1) << 6) | d2]; float2 pp2 = sPre2[cp + 1];
      p0 += pp2.x * b2f((ushort_t)(w2 & 0xffffu));
      p1 += pp2.y * b2f((ushort_t)(w2 >> 16));
    }
    sPart[t] = p0 + p1;
    __syncthreads();
    if (t < 64) {
      float r = (beo + sPart[t] + sPart[64 + t] + sPart[128 + t] + sPart[192 + t]) * mi * mj;
      newE[((size_t)blk * NN + j) * DE + t] = r;
    }
  }
  float wv = accv / l;
  wvs[(size_t)blk * DX + t] = yx * wv;
  if (t < DE) {
    float* eb = est + (size_t)blk * 256;
    eb[t] = es_s; eb[64 + t] = es_mn; eb[128 + t] = es_mx; eb[192 + t] = es_ss;
  }
}

// ---------------- newX = (wv_scaled @ W_x_out + b) * x_mask ----------------
__global__ __launch_bounds__(256) void k_newx(const float* wvs, const float* Wxo,
    const float* bxo, const float* nmask, float* newX) {
  int blk = blockIdx.x; int t = threadIdx.x;
  __shared__ float sR[DX];
  sR[t] = wvs[(size_t)blk * DX + t];
  __syncthreads();
  float acc = bxo[t];
  #pragma unroll 4
  for (int k = 0; k < DX; ++k) acc += sR[k] * Wxo[k * DX + t];
  float mi = nmask[blk];
  newX[(size_t)blk * DX + t] = acc * mi;
}

// ---------------- y path ----------------
__global__ __launch_bounds__(64) void k_y(const float* y, const float* xs, const float* est,
    const float* Wyy, const float* byy, const float* Wxy, const float* bxy,
    const float* Wey, const float* bey, const float* W1, const float* b1,
    const float* W2, const float* b2_, float* out) {
  int b = blockIdx.x; int d = threadIdx.x; // 64 threads
  float s = 0.f, ss = 0.f, mn = 1e30f, mx = -1e30f;
  for (int i = 0; i < NN; ++i) {
    const float* eb = est + ((size_t)(b * NN + i)) * 256;
    s += eb[d]; mn = fminf(mn, eb[64 + d]); mx = fmaxf(mx, eb[128 + d]); ss += eb[192 + d];
  }
  const float cnt = (float)(NN * NN);
  float mean = s / cnt;
  float var = (ss - cnt * mean * mean) / (cnt - 1.f);
  var = fmaxf(var, 0.f);
  __shared__ float es[256];
  es[d] = mean; es[64 + d] = mn; es[128 + d] = mx; es[192 + d] = sqrtf(var);
  __shared__ float sy[DY];
  sy[d] = y[b * DY + d];
  __syncthreads();
  float acc = byy[d] + bxy[d] + bey[d];
  #pragma unroll
  for (int k = 0; k < DY; ++k) acc += sy[k] * Wyy[k * DY + d];
  const float* xb = xs + b * 1024;
  for (int k = 0; k < 1024; ++k) acc += xb[k] * Wxy[k * DY + d];
  for (int k = 0; k < 256; ++k) acc += es[k] * Wey[k * DY + d];
  __shared__ float sny[DY];
  sny[d] = acc;
  __syncthreads();
  float h = b1[d];
  #pragma unroll
  for (int k = 0; k < DY; ++k) h += sny[k] * W1[k * DY + d];
  h = fmaxf(h, 0.f);
  __shared__ float sh[DY];
  sh[d] = h;
  __syncthreads();
  float o = b2_[d];
  #pragma unroll
  for (int k = 0; k < DY; ++k) o += sh[k] * W2[k * DY + d];
  out[b * DY + d] = o;
}

extern "C" void kernel_launch(void* const* d_in, const int* in_sizes, int n_in,
                              void* d_out, int out_size, void* d_ws, size_t ws_size,
                              hipStream_t stream) {
  (void)in_sizes; (void)n_in; (void)out_size; (void)ws_size;
  const float* X   = (const float*)d_in[0];
  const float* E   = (const float*)d_in[1];
  const float* y   = (const float*)d_in[2];
  const float* nm  = (const float*)d_in[3];
  const float* Wq  = (const float*)d_in[4];  const float* bq  = (const float*)d_in[5];
  const float* Wk  = (const float*)d_in[6];  const float* bk  = (const float*)d_in[7];
  const float* Wv  = (const float*)d_in[8];  const float* bv  = (const float*)d_in[9];
  const float* Wem = (const float*)d_in[10]; const float* bem = (const float*)d_in[11];
  const float* Wye = (const float*)d_in[12]; const float* bye = (const float*)d_in[13];
  const float* Wyx = (const float*)d_in[14]; const float* byx = (const float*)d_in[15];
  const float* Wyy = (const float*)d_in[16]; const float* byy = (const float*)d_in[17];
  const float* Wxy = (const float*)d_in[18]; const float* bxy = (const float*)d_in[19];
  const float* Wey = (const float*)d_in[20]; const float* bey = (const float*)d_in[21];
  const float* Wxo = (const float*)d_in[22]; const float* bxo = (const float*)d_in[23];
  const float* Weo = (const float*)d_in[24]; const float* beo = (const float*)d_in[25];
  const float* W1  = (const float*)d_in[26]; const float* b1  = (const float*)d_in[27];
  const float* W2  = (const float*)d_in[28]; const float* b2  = (const float*)d_in[29];

  float* ws   = (float*)d_ws;
  float* Q    = ws;                 // 262144
  float* K    = Q + 262144;         // 262144
  float* V    = K + 262144;         // 262144
  float* yep1 = V + 262144;         // 1024
  float* yxp1 = yep1 + 1024;        // 1024
  float* xs   = yxp1 + 1024;        // 4096
  float* wvs  = xs + 4096;          // 262144
  float* est  = wvs + 262144;       // 262144

  float* newX = (float*)d_out;
  float* newE = newX + 262144;
  float* newy = newE + 16777216;

  k_qkv<<<BS * NN, 256, 0, stream>>>(X, nm, Wq, bq, Wk, bk, Wv, bv, Q, K, V);
  k_xstats<<<BS, 256, 0, stream>>>(X, xs);
  k_ymul<<<BS, 256, 0, stream>>>(y, Wye, bye, Wyx, byx, yep1, yxp1);
  k_main<<<BS * NN, 256, 0, stream>>>(E, nm, Wem, bem, Weo, beo, Q, K, V, yep1, yxp1,
                                      newE, wvs, est);
  k_newx<<<BS * NN, 256, 0, stream>>>(wvs, Wxo, bxo, nm, newX);
  k_y<<<BS, 64, 0, stream>>>(y, xs, est, Wyy, byy, Wxy, bxy, Wey, bey, W1, b1, W2, b2, newy);
}

// Round 3
// 242.118 us; speedup vs baseline: 4.3405x; 4.3405x over previous
//
#include <hip/hip_runtime.h>

#define BS 4
#define NN 256
#define DX 256
#define DE 64
#define DY 64
#define INV_SQRT_DF 0.17677669529663687f

typedef unsigned short ushort_t;
typedef unsigned int uint32;
typedef short v4s __attribute__((ext_vector_type(4)));
typedef float v4f __attribute__((ext_vector_type(4)));

__device__ __forceinline__ float b2f(ushort_t u) {
  union { uint32 i; float f; } v; v.i = ((uint32)u) << 16; return v.f;
}
__device__ __forceinline__ ushort_t f2b(float f) {
  union { float f; uint32 i; } v; v.f = f;
  uint32 x = v.i;
  x += ((x >> 16) & 1u) + 0x7FFFu;   // round-to-nearest-even
  return (ushort_t)(x >> 16);
}

// ---------------- Q/K/V projections: (X @ W + b) * x_mask ----------------
__global__ __launch_bounds__(256) void k_qkv(const float* __restrict__ X, const float* __restrict__ nmask,
    const float* __restrict__ Wq, const float* __restrict__ bq, const float* __restrict__ Wk, const float* __restrict__ bk,
    const float* __restrict__ Wv, const float* __restrict__ bv, float* Q, float* K, float* V) {
  int blk = blockIdx.x;            // b*N + i
  int t = threadIdx.x;
  __shared__ float sX[DX];
  sX[t] = X[(size_t)blk * DX + t];
  __syncthreads();
  float m = nmask[blk];
  float aq = bq[t], ak = bk[t], av = bv[t];
  #pragma unroll 4
  for (int k = 0; k < DX; ++k) {
    float x = sX[k];
    aq += x * Wq[k * DX + t];
    ak += x * Wk[k * DX + t];
    av += x * Wv[k * DX + t];
  }
  size_t o = (size_t)blk * DX + t;
  Q[o] = aq * m; K[o] = ak * m; V[o] = av * m;
}

// ---------------- X stats ----------------
__global__ __launch_bounds__(256) void k_xstats(const float* __restrict__ X, float* xs) {
  int b = blockIdx.x; int d = threadIdx.x;
  float s = 0.f, ss = 0.f, mn = 1e30f, mx = -1e30f;
  for (int i = 0; i < NN; ++i) {
    float v = X[((size_t)b * NN + i) * DX + d];
    s += v; ss += v * v; mn = fminf(mn, v); mx = fmaxf(mx, v);
  }
  float mean = s / (float)NN;
  float var = (ss - (float)NN * mean * mean) / (float)(NN - 1);
  var = fmaxf(var, 0.f);
  float* o = xs + b * 4 * DX;
  o[d] = mean; o[DX + d] = mn; o[2 * DX + d] = mx; o[3 * DX + d] = sqrtf(var);
}

// ---------------- ye2+1, yx2+1 ----------------
__global__ __launch_bounds__(256) void k_ymul(const float* __restrict__ y,
    const float* __restrict__ Wye, const float* __restrict__ bye,
    const float* __restrict__ Wyx, const float* __restrict__ byx, float* yep1, float* yxp1) {
  int b = blockIdx.x; int t = threadIdx.x;
  __shared__ float sy[DY];
  if (t < DY) sy[t] = y[b * DY + t];
  __syncthreads();
  float ae = bye[t], ax = byx[t];
  #pragma unroll
  for (int k = 0; k < DY; ++k) {
    float v = sy[k];
    ae += v * Wye[k * DX + t];
    ax += v * Wyx[k * DX + t];
  }
  yep1[b * DX + t] = ae + 1.0f;
  yxp1[b * DX + t] = ax + 1.0f;
}

// ---------------- fused main (MFMA) ----------------
// 512 threads = 8 waves per (b,i). Wave w owns c-range [w*32, w*32+32) for GEMM1/softmax,
// and (j-quarter w>>1, d-half w&1) for GEMM2.
// LDS: ET[64j][64k] bf16 swizzled @0 (8KB); PRE[64j][256c] bf16 swizzled @8192 (32KB);
//      RED 2048 f32 @40960 (8KB). Total 48KB.
#define ET_OFF 0
#define PRE_OFF 8192
#define RED_OFF 40960

__global__ __launch_bounds__(512, 2) void k_main(
    const float* __restrict__ E, const float* __restrict__ nmask,
    const float* __restrict__ Wemul, const float* __restrict__ bemul,
    const float* __restrict__ Weout, const float* __restrict__ beout,
    const float* __restrict__ Q, const float* __restrict__ Kf, const float* __restrict__ Vf,
    const float* __restrict__ yep1, const float* __restrict__ yxp1,
    float* __restrict__ newE, float* __restrict__ wvs, float* __restrict__ est) {
  __shared__ char SM[49152];
  int t = threadIdx.x;
  int blk = blockIdx.x; int b = blk >> 8; int i = blk & 255;
  int w = t >> 6, lane = t & 63, lg = lane >> 4, lr = lane & 15;

  float mi = nmask[(b << 8) + i];

  // per-lane constants (GEMM1/softmax side)
  int cc[2]; float qv[2], yev[2], yxv[2], bemv[2];
  #pragma unroll
  for (int cr = 0; cr < 2; ++cr) {
    int c = (w << 5) + (cr << 4) + lr;
    cc[cr] = c;
    qv[cr]  = Q[(size_t)blk * DX + c];
    yev[cr] = yep1[(b << 8) + c];
    yxv[cr] = yxp1[(b << 8) + c];
    bemv[cr] = bemul[c];
  }
  // GEMM2 side
  int jq = w >> 1, dh = w & 1;
  int dd[2]; float beoV[2];
  #pragma unroll
  for (int dr = 0; dr < 2; ++dr) { int d = (dh << 5) + (dr << 4) + lr; dd[dr] = d; beoV[dr] = beout[d]; }

  // hoisted B-fragments, loaded straight from global (f32 -> bf16 pack)
  // GEMM1 B = Wemul[k][c] (64x256): lane needs k = ks*16 + 4*lg + i, col cc[cr]
  v4s bfr1[2][4];
  #pragma unroll
  for (int cr = 0; cr < 2; ++cr)
    #pragma unroll
    for (int ks = 0; ks < 4; ++ks) {
      int k0 = (ks << 4) + (lg << 2);
      v4s f;
      #pragma unroll
      for (int e = 0; e < 4; ++e) f[e] = (short)f2b(Wemul[(k0 + e) * DX + cc[cr]]);
      bfr1[cr][ks] = f;
    }
  // GEMM2 B = Weout[c][d] (256x64): lane needs c = ks*16 + 4*lg + i, col dd[dr]
  v4s bfr2[2][16];
  #pragma unroll
  for (int dr = 0; dr < 2; ++dr)
    #pragma unroll
    for (int ks = 0; ks < 16; ++ks) {
      int c0 = (ks << 4) + (lg << 2);
      v4s f;
      #pragma unroll
      for (int e = 0; e < 4; ++e) f[e] = (short)f2b(Weout[(c0 + e) * DE + dd[dr]]);
      bfr2[dr][ks] = f;
    }

  float mloc[2] = {-3e38f, -3e38f}, lloc[2] = {0.f, 0.f}, avloc[2] = {0.f, 0.f};
  float es_s = 0.f, es_ss = 0.f, es_mn = 3e38f, es_mx = -3e38f;

  const float* Erow = E + (size_t)blk * (NN * DE);
  const v4f vzero = {0.f, 0.f, 0.f, 0.f};

  for (int jt = 0; jt < 4; ++jt) {
    __syncthreads();   // prior GEMM1 (ET) and GEMM2 (PRE) reads complete
    // ---- stage E tile (f32 global -> bf16 LDS, swizzled) + E-stat partials ----
    #pragma unroll
    for (int it = 0; it < 8; ++it) {
      int idx = t + (it << 9);
      int jl = idx >> 6, k = idx & 63;
      float v = Erow[(jt << 12) + idx];
      es_s += v; es_ss += v * v; es_mn = fminf(es_mn, v); es_mx = fmaxf(es_mx, v);
      *(ushort_t*)(SM + ET_OFF + (((jl << 7) + (k << 1)) ^ ((jl & 7) << 4))) = f2b(v);
    }
    __syncthreads();

    // ---- GEMM1: E1 = ET(64x64) @ Wemul(64x256), wave's 32-col slice ----
    v4f acc1[4][2];
    #pragma unroll
    for (int jr = 0; jr < 4; ++jr)
      #pragma unroll
      for (int cr = 0; cr < 2; ++cr) acc1[jr][cr] = vzero;
    #pragma unroll
    for (int ks = 0; ks < 4; ++ks) {
      v4s aA[4];
      #pragma unroll
      for (int jr = 0; jr < 4; ++jr) {
        int jl = (jr << 4) + lr;
        aA[jr] = *(const v4s*)(SM + ET_OFF + (((jl << 7) + (ks << 5) + (lg << 3)) ^ ((jl & 7) << 4)));
      }
      #pragma unroll
      for (int jr = 0; jr < 4; ++jr)
        #pragma unroll
        for (int cr = 0; cr < 2; ++cr)
          acc1[jr][cr] = __builtin_amdgcn_mfma_f32_16x16x16bf16_1k(aA[jr], bfr1[cr][ks], acc1[jr][cr], 0, 0, 0);
    }

    // ---- elementwise: Y, online softmax partials, pre -> LDS ----
    #pragma unroll
    for (int jr = 0; jr < 4; ++jr) {
      #pragma unroll
      for (int reg = 0; reg < 4; ++reg) {
        int jl = (jr << 4) + (lg << 2) + reg;
        int j = (jt << 6) + jl;
        float mj = nmask[(b << 8) + j];
        size_t rowKV = (((size_t)(b << 8) + j) << 8);
        #pragma unroll
        for (int cr = 0; cr < 2; ++cr) {
          float E1 = (acc1[jr][cr][reg] + bemv[cr]) * (mi * mj);
          float Yv = qv[cr] * Kf[rowKV + cc[cr]] * INV_SQRT_DF * (E1 + 1.0f);
          *(ushort_t*)(SM + PRE_OFF + (((jl << 9) + (cc[cr] << 1)) ^ ((jl & 7) << 4))) = f2b(yev[cr] * Yv);
          float Ym = (mj > 0.f) ? Yv : -3e38f;
          float nm = fmaxf(mloc[cr], Ym);
          float corr = __expf(mloc[cr] - nm);
          float p = mj * __expf(Ym - nm);
          lloc[cr] = lloc[cr] * corr + p;
          avloc[cr] = avloc[cr] * corr + p * Vf[rowKV + cc[cr]];
          mloc[cr] = nm;
        }
      }
    }
    __syncthreads();   // PRE ready

    // ---- GEMM2: newE_tile = PRE(64x256) @ Weout(256x64); wave: 16j x 32d ----
    v4f acc2[2] = {vzero, vzero};
    #pragma unroll
    for (int ks = 0; ks < 16; ++ks) {
      int jl = (jq << 4) + lr;
      v4s aA = *(const v4s*)(SM + PRE_OFF + (((jl << 9) + (ks << 5) + (lg << 3)) ^ ((jl & 7) << 4)));
      acc2[0] = __builtin_amdgcn_mfma_f32_16x16x16bf16_1k(aA, bfr2[0][ks], acc2[0], 0, 0, 0);
      acc2[1] = __builtin_amdgcn_mfma_f32_16x16x16bf16_1k(aA, bfr2[1][ks], acc2[1], 0, 0, 0);
    }
    // epilogue: write newE rows of this j-tile
    #pragma unroll
    for (int reg = 0; reg < 4; ++reg) {
      int j = (jt << 6) + (jq << 4) + (lg << 2) + reg;
      float mj = nmask[(b << 8) + j];
      float mm = mi * mj;
      size_t orow = (((size_t)blk << 8) + j) << 6;
      #pragma unroll
      for (int dr = 0; dr < 2; ++dr)
        newE[orow + dd[dr]] = (acc2[dr][reg] + beoV[dr]) * mm;
    }
  }

  // ---- softmax merge across the 4 lane-groups; write wvs ----
  #pragma unroll
  for (int cr = 0; cr < 2; ++cr) {
    #pragma unroll
    for (int off = 16; off <= 32; off <<= 1) {
      float m2 = __shfl_xor(mloc[cr], off, 64);
      float l2 = __shfl_xor(lloc[cr], off, 64);
      float a2 = __shfl_xor(avloc[cr], off, 64);
      float nm = fmaxf(mloc[cr], m2);
      float f1 = __expf(mloc[cr] - nm), f2n = __expf(m2 - nm);
      lloc[cr] = lloc[cr] * f1 + l2 * f2n;
      avloc[cr] = avloc[cr] * f1 + a2 * f2n;
      mloc[cr] = nm;
    }
    if (lg == 0)
      wvs[(size_t)blk * DX + cc[cr]] = yxv[cr] * (avloc[cr] / lloc[cr]);
  }

  // ---- E-stat block reduction ----
  float* RED = (float*)(SM + RED_OFF);
  RED[t] = es_s; RED[512 + t] = es_mn; RED[1024 + t] = es_mx; RED[1536 + t] = es_ss;
  __syncthreads();
  if (t < 64) {
    float s = 0.f, ss = 0.f, mn = 3e38f, mx = -3e38f;
    #pragma unroll
    for (int q = 0; q < 8; ++q) {
      s  += RED[t + (q << 6)];
      mn  = fminf(mn, RED[512 + t + (q << 6)]);
      mx  = fmaxf(mx, RED[1024 + t + (q << 6)]);
      ss += RED[1536 + t + (q << 6)];
    }
    float* eb = est + ((size_t)blk << 8);
    eb[t] = s; eb[64 + t] = mn; eb[128 + t] = mx; eb[192 + t] = ss;
  }
}

// ---------------- newX = (wv_scaled @ W_x_out + b) * x_mask ----------------
__global__ __launch_bounds__(256) void k_newx(const float* __restrict__ wvs, const float* __restrict__ Wxo,
    const float* __restrict__ bxo, const float* __restrict__ nmask, float* newX) {
  int blk = blockIdx.x; int t = threadIdx.x;
  __shared__ float sR[DX];
  sR[t] = wvs[(size_t)blk * DX + t];
  __syncthreads();
  float acc = bxo[t];
  #pragma unroll 4
  for (int k = 0; k < DX; ++k) acc += sR[k] * Wxo[k * DX + t];
  float mi = nmask[blk];
  newX[(size_t)blk * DX + t] = acc * mi;
}

// ---------------- y path ----------------
__global__ __launch_bounds__(64) void k_y(const float* __restrict__ y, const float* __restrict__ xs, const float* __restrict__ est,
    const float* __restrict__ Wyy, const float* __restrict__ byy, const float* __restrict__ Wxy, const float* __restrict__ bxy,
    const float* __restrict__ Wey, const float* __restrict__ bey, const float* __restrict__ W1, const float* __restrict__ b1,
    const float* __restrict__ W2, const float* __restrict__ b2_, float* out) {
  int b = blockIdx.x; int d = threadIdx.x; // 64 threads
  float s = 0.f, ss = 0.f, mn = 1e30f, mx = -1e30f;
  for (int i = 0; i < NN; ++i) {
    const float* eb = est + ((size_t)(b * NN + i)) * 256;
    s += eb[d]; mn = fminf(mn, eb[64 + d]); mx = fmaxf(mx, eb[128 + d]); ss += eb[192 + d];
  }
  const float cnt = (float)(NN * NN);
  float mean = s / cnt;
  float var = (ss - cnt * mean * mean) / (cnt - 1.f);
  var = fmaxf(var, 0.f);
  __shared__ float es[256];
  es[d] = mean; es[64 + d] = mn; es[128 + d] = mx; es[192 + d] = sqrtf(var);
  __shared__ float sy[DY];
  sy[d] = y[b * DY + d];
  __syncthreads();
  float acc = byy[d] + bxy[d] + bey[d];
  #pragma unroll
  for (int k = 0; k < DY; ++k) acc += sy[k] * Wyy[k * DY + d];
  const float* xb = xs + b * 1024;
  for (int k = 0; k < 1024; ++k) acc += xb[k] * Wxy[k * DY + d];
  for (int k = 0; k < 256; ++k) acc += es[k] * Wey[k * DY + d];
  __shared__ float sny[DY];
  sny[d] = acc;
  __syncthreads();
  float h = b1[d];
  #pragma unroll
  for (int k = 0; k < DY; ++k) h += sny[k] * W1[k * DY + d];
  h = fmaxf(h, 0.f);
  __shared__ float sh[DY];
  sh[d] = h;
  __syncthreads();
  float o = b2_[d];
  #pragma unroll
  for (int k = 0; k < DY; ++k) o += sh[k] * W2[k * DY + d];
  out[b * DY + d] = o;
}

extern "C" void kernel_launch(void* const* d_in, const int* in_sizes, int n_in,
                              void* d_out, int out_size, void* d_ws, size_t ws_size,
                              hipStream_t stream) {
  (void)in_sizes; (void)n_in; (void)out_size; (void)ws_size;
  const float* X   = (const float*)d_in[0];
  const float* E   = (const float*)d_in[1];
  const float* y   = (const float*)d_in[2];
  const float* nm  = (const float*)d_in[3];
  const float* Wq  = (const float*)d_in[4];  const float* bq  = (const float*)d_in[5];
  const float* Wk  = (const float*)d_in[6];  const float* bk  = (const float*)d_in[7];
  const float* Wv  = (const float*)d_in[8];  const float* bv  = (const float*)d_in[9];
  const float* Wem = (const float*)d_in[10]; const float* bem = (const float*)d_in[11];
  const float* Wye = (const float*)d_in[12]; const float* bye = (const float*)d_in[13];
  const float* Wyx = (const float*)d_in[14]; const float* byx = (const float*)d_in[15];
  const float* Wyy = (const float*)d_in[16]; const float* byy = (const float*)d_in[17];
  const float* Wxy = (const float*)d_in[18]; const float* bxy = (const float*)d_in[19];
  const float* Wey = (const float*)d_in[20]; const float* bey = (const float*)d_in[21];
  const float* Wxo = (const float*)d_in[22]; const float* bxo = (const float*)d_in[23];
  const float* Weo = (const float*)d_in[24]; const float* beo = (const float*)d_in[25];
  const float* W1  = (const float*)d_in[26]; const float* b1  = (const float*)d_in[27];
  const float* W2  = (const float*)d_in[28]; const float* b2  = (const float*)d_in[29];

  float* ws   = (float*)d_ws;
  float* Q    = ws;                 // 262144
  float* K    = Q + 262144;         // 262144
  float* V    = K + 262144;         // 262144
  float* yep1 = V + 262144;         // 1024
  float* yxp1 = yep1 + 1024;        // 1024
  float* xs   = yxp1 + 1024;        // 4096
  float* wvs  = xs + 4096;          // 262144
  float* est  = wvs + 262144;       // 262144

  float* newX = (float*)d_out;
  float* newE = newX + 262144;
  float* newy = newE + 16777216;

  k_qkv<<<BS * NN, 256, 0, stream>>>(X, nm, Wq, bq, Wk, bk, Wv, bv, Q, K, V);
  k_xstats<<<BS, 256, 0, stream>>>(X, xs);
  k_ymul<<<BS, 256, 0, stream>>>(y, Wye, bye, Wyx, byx, yep1, yxp1);
  k_main<<<BS * NN, 512, 0, stream>>>(E, nm, Wem, bem, Weo, beo, Q, K, V, yep1, yxp1,
                                      newE, wvs, est);
  k_newx<<<BS * NN, 256, 0, stream>>>(wvs, Wxo, bxo, nm, newX);
  k_y<<<BS, 64, 0, stream>>>(y, xs, est, Wyy, byy, Wxy, bxy, Wey, bey, W1, b1, W2, b2, newy);
}